// Round 1
// baseline (35202.716 us; speedup 1.0000x reference)
//
#include <hip/hip_runtime.h>
#include <cstddef>

// ---------------------------------------------------------------------------
// WaveletNet forward on MI355X — round 0: correct fp32 skeleton.
// wt/iwt = Haar 2x2 block mixes (elementwise). conv3x3 = direct conv,
// 16x16 tile, 4 staged input channels per barrier, 8 output chans/thread.
// ---------------------------------------------------------------------------

#define TS 16
#define CPC 4

template<int OCPT>
__global__ __launch_bounds__(256)
void conv3x3_k(const float* __restrict__ in0, int C0,
               const float* __restrict__ in1, int C1,
               const float* __restrict__ wgt, const float* __restrict__ bias,
               const float* __restrict__ skip, float* __restrict__ out,
               int H, int W, int Cout, int relu)
{
    __shared__ float tile[CPC][TS + 2][TS + 3];   // 18 rows, 19-col pad (bank stride)
    const int tid = threadIdx.x;
    const int tx = tid & 15, ty = tid >> 4;
    const int ntx = W / TS;
    const int tX = (blockIdx.x % ntx) * TS;
    const int tY = (blockIdx.x / ntx) * TS;
    const int ocBase = blockIdx.y * OCPT;
    const int b = blockIdx.z;
    const int Cin = C0 + C1;
    const size_t planeHW = (size_t)H * W;

    float acc[OCPT];
#pragma unroll
    for (int i = 0; i < OCPT; ++i) acc[i] = bias[ocBase + i];

    for (int cb = 0; cb < Cin; cb += CPC) {
        // stage CPC channels of the 18x18 halo tile into LDS
        for (int i = tid; i < CPC * 324; i += 256) {
            int c = i / 324;
            int r = i - c * 324;
            int ly = r / 18, lx = r - ly * 18;
            int ci = cb + c;
            int gy = tY + ly - 1, gx = tX + lx - 1;
            float v = 0.f;
            if (gy >= 0 && gy < H && gx >= 0 && gx < W) {
                const float* src = (ci < C0)
                    ? in0 + ((size_t)b * C0 + ci) * planeHW
                    : in1 + ((size_t)b * C1 + (ci - C0)) * planeHW;
                v = src[(size_t)gy * W + gx];
            }
            tile[c][ly][lx] = v;
        }
        __syncthreads();
#pragma unroll
        for (int c = 0; c < CPC; ++c) {
            float x00 = tile[c][ty + 0][tx + 0], x01 = tile[c][ty + 0][tx + 1], x02 = tile[c][ty + 0][tx + 2];
            float x10 = tile[c][ty + 1][tx + 0], x11 = tile[c][ty + 1][tx + 1], x12 = tile[c][ty + 1][tx + 2];
            float x20 = tile[c][ty + 2][tx + 0], x21 = tile[c][ty + 2][tx + 1], x22 = tile[c][ty + 2][tx + 2];
            int ci = cb + c;
#pragma unroll
            for (int o = 0; o < OCPT; ++o) {
                const float* wp = wgt + ((size_t)(ocBase + o) * Cin + ci) * 9;
                acc[o] += wp[0] * x00 + wp[1] * x01 + wp[2] * x02
                        + wp[3] * x10 + wp[4] * x11 + wp[5] * x12
                        + wp[6] * x20 + wp[7] * x21 + wp[8] * x22;
            }
        }
        __syncthreads();
    }

    const int oy = tY + ty, ox = tX + tx;
    size_t outBase = ((size_t)b * Cout + ocBase) * planeHW + (size_t)oy * W + ox;
#pragma unroll
    for (int o = 0; o < OCPT; ++o) {
        float v = acc[o];
        if (skip) v += skip[outBase + (size_t)o * planeHW];
        if (relu) v = v > 0.f ? v : 0.2f * v;
        out[outBase + (size_t)o * planeHW] = v;
    }
}

// wt: [B,C,2Ho,2Wo] -> [B,4C,Ho,Wo];  LL, then HF bands rescaled (y+1)/2
__global__ void wt_k(const float* __restrict__ in, float* __restrict__ out,
                     int C, int Ho, int Wo, int total)
{
    int idx = blockIdx.x * 256 + threadIdx.x;
    if (idx >= total) return;
    int w = idx % Wo;
    int t = idx / Wo;
    int h = t % Ho; t /= Ho;
    int c = t % C;
    int b = t / C;
    const int Wi = Wo * 2;
    const float* p = in + ((size_t)b * C + c) * (size_t)(Ho * 2) * Wi;
    float a  = p[(size_t)(2 * h) * Wi + 2 * w];
    float bv = p[(size_t)(2 * h) * Wi + 2 * w + 1];
    float cv = p[(size_t)(2 * h + 1) * Wi + 2 * w];
    float d  = p[(size_t)(2 * h + 1) * Wi + 2 * w + 1];
    float y0 = 0.25f * (a + bv + cv + d);
    float y1 = 0.25f * (a + bv - cv - d) + 0.5f;
    float y2 = 0.25f * (a - bv + cv - d) + 0.5f;
    float y3 = 0.25f * (a - bv - cv + d) + 0.5f;
    size_t phw = (size_t)Ho * Wo;
    size_t ob = (((size_t)b * (4 * C) + 4 * c) * Ho + h) * Wo + w;
    out[ob]           = y0;
    out[ob + phw]     = y1;
    out[ob + 2 * phw] = y2;
    out[ob + 3 * phw] = y3;
}

// iwt: [B,4C,H,W] -> [B,C,2H,2W]; HF bands un-rescaled (2y-1); optional sigmoid
__global__ void iwt_k(const float* __restrict__ in, float* __restrict__ out,
                      int C, int H, int W, int total, int do_sigmoid)
{
    int idx = blockIdx.x * 256 + threadIdx.x;
    if (idx >= total) return;
    int w = idx % W;
    int t = idx / W;
    int h = t % H; t /= H;
    int c = t % C;
    int b = t / C;
    size_t phw = (size_t)H * W;
    size_t ib = (((size_t)b * (4 * C) + 4 * c) * H + h) * W + w;
    float y0 = in[ib];
    float y1 = 2.f * in[ib + phw]     - 1.f;
    float y2 = 2.f * in[ib + 2 * phw] - 1.f;
    float y3 = 2.f * in[ib + 3 * phw] - 1.f;
    float x00 = y0 + 0.5f * ( y1 + y2 + y3);
    float x01 = y0 + 0.5f * ( y1 - y2 - y3);
    float x10 = y0 + 0.5f * (-y1 + y2 - y3);
    float x11 = y0 + 0.5f * (-y1 - y2 + y3);
    if (do_sigmoid) {
        x00 = 1.f / (1.f + __expf(-x00));
        x01 = 1.f / (1.f + __expf(-x01));
        x10 = 1.f / (1.f + __expf(-x10));
        x11 = 1.f / (1.f + __expf(-x11));
    }
    const int Wo = 2 * W;
    float* q = out + ((size_t)b * C + c) * (size_t)(2 * H) * Wo;
    q[(size_t)(2 * h) * Wo + 2 * w]         = x00;
    q[(size_t)(2 * h) * Wo + 2 * w + 1]     = x01;
    q[(size_t)(2 * h + 1) * Wo + 2 * w]     = x10;
    q[(size_t)(2 * h + 1) * Wo + 2 * w + 1] = x11;
}

extern "C" void kernel_launch(void* const* d_in, const int* in_sizes, int n_in,
                              void* d_out, int out_size, void* d_ws, size_t ws_size,
                              hipStream_t stream)
{
    const float* x   = (const float*)d_in[0];
    const float* c1w = (const float*)d_in[1];  const float* c1b = (const float*)d_in[2];
    const float* c2w = (const float*)d_in[3];  const float* c2b = (const float*)d_in[4];
    const float* c3w = (const float*)d_in[5];  const float* c3b = (const float*)d_in[6];
    const float* c4w = (const float*)d_in[7];  const float* c4b = (const float*)d_in[8];
    const float* d1w = (const float*)d_in[9];  const float* d1b = (const float*)d_in[10];
    const float* d2w = (const float*)d_in[11]; const float* d2b = (const float*)d_in[12];
    const float* d3w = (const float*)d_in[13]; const float* d3b = (const float*)d_in[14];
    const float* d4w = (const float*)d_in[15]; const float* d4b = (const float*)d_in[16];

    const size_t S = 8388608;                 // 32 MB slots (floats)
    float* s0 = (float*)d_ws;
    float* s1 = s0 + S;  float* s2 = s1 + S;  float* s3 = s2 + S;
    float* s4 = s3 + S;  float* s5 = s4 + S;
    float* outp = (float*)d_out;
    const int B = 8;

    auto wt = [&](const float* in, float* out, int C, int Ho, int Wo) {
        int total = B * C * Ho * Wo;
        wt_k<<<dim3((total + 255) / 256), 256, 0, stream>>>(in, out, C, Ho, Wo, total);
    };
    auto iwt = [&](const float* in, float* out, int C, int H, int W, int sig) {
        int total = B * C * H * W;
        iwt_k<<<dim3((total + 255) / 256), 256, 0, stream>>>(in, out, C, H, W, total, sig);
    };
    auto conv8 = [&](const float* in0, int C0, const float* in1, int C1,
                     const float* w, const float* bi, const float* skip,
                     float* out, int H, int W, int Cout, int relu) {
        dim3 g((W / 16) * (H / 16), Cout / 8, B);
        conv3x3_k<8><<<g, 256, 0, stream>>>(in0, C0, in1, C1, w, bi, skip, out, H, W, Cout, relu);
    };

    wt(x, s0, 1, 256, 256);                                        // w1  -> s0
    conv8(s0, 4,   s0, 0,   c1w, c1b, nullptr, s1, 256, 256, 16, 1);   // c1  -> s1
    wt(s1, s0, 16, 128, 128);                                      // w2  -> s0
    conv8(s0, 64,  s0, 0,   c2w, c2b, nullptr, s2, 128, 128, 64, 1);   // c2  -> s2
    wt(s2, s0, 64, 64, 64);                                        // w3  -> s0
    conv8(s0, 256, s0, 0,   c3w, c3b, nullptr, s3, 64, 64, 256, 1);    // c3  -> s3
    wt(s3, s0, 256, 32, 32);                                       // w4  -> s0
    conv8(s0, 1024, s0, 0,  c4w, c4b, nullptr, s4, 32, 32, 1024, 1);   // c4  -> s4
    conv8(s4, 1024, s4, 0,  c4w, c4b, nullptr, s5, 32, 32, 1024, 1);   // c5  -> s5
    conv8(s5, 1024, s5, 0,  c4w, c4b, s0,      s4, 32, 32, 1024, 1);   // ic4 = lrelu(conv4(c5)+w4) -> s4
    iwt(s4, s5, 256, 32, 32, 0);                                   // u4  -> s5
    conv8(s3, 256, s5, 256, d4w, d4b, nullptr, s0, 64, 64, 256, 1);    // ic3 -> s0 (w4 dead)
    iwt(s0, s4, 64, 64, 64, 0);                                    // u3  -> s4
    conv8(s2, 64,  s4, 64,  d3w, d3b, nullptr, s3, 128, 128, 64, 1);   // ic2 -> s3 (c3 dead)
    iwt(s3, s0, 16, 128, 128, 0);                                  // u2  -> s0
    conv8(s1, 16,  s0, 16,  d2w, d2b, nullptr, s2, 256, 256, 16, 1);   // ic1 -> s2 (c2 dead)
    {   // convd1: Cout=4 -> OCPT=4
        dim3 g((256 / 16) * (256 / 16), 1, B);
        conv3x3_k<4><<<g, 256, 0, stream>>>(s2, 16, s2, 0, d1w, d1b, nullptr, s1, 256, 256, 4, 1);
    }
    iwt(s1, outp, 1, 256, 256, 1);                                 // sigmoid(iwt(iw1)) -> d_out
}

// Round 2
// 1611.143 us; speedup vs baseline: 21.8495x; 21.8495x over previous
//
#include <hip/hip_runtime.h>
#include <cstddef>

// ---------------------------------------------------------------------------
// WaveletNet on MI355X — round 2: bf16 MFMA implicit-GEMM convs, NHWC layout.
// Big convs (conv2/3/4, convd3/4) -> mfma_f32_16x16x32_bf16, m97 structure.
// Concats are free: producers write channel slices of shared NHWC buffers.
// ---------------------------------------------------------------------------

typedef unsigned short u16;
typedef __bf16 bf16x8 __attribute__((ext_vector_type(8)));
typedef float floatx4 __attribute__((ext_vector_type(4)));
typedef u16 u16x4 __attribute__((ext_vector_type(4)));
typedef u16 u16x8 __attribute__((ext_vector_type(8)));
typedef unsigned int uint4v __attribute__((ext_vector_type(4)));

__device__ __forceinline__ float b2f(u16 h) {
    union { unsigned u; float f; } x; x.u = ((unsigned)h) << 16; return x.f;
}
__device__ __forceinline__ u16 f2b(float f) {
    union { float f; unsigned u; } x; x.f = f;
    return (u16)((x.u + 0x7FFFu + ((x.u >> 16) & 1u)) >> 16);
}
__device__ __forceinline__ float lrelu_f(float v) { return v > 0.f ? v : 0.2f * v; }

// ---------------- MFMA implicit-GEMM conv3x3, NHWC ----------------
// C[m][n] = sum_k A[m][k] * Wb[n][k],  k = tap*Cin + ci  (Wb = [Cout][9*Cin])
// BM=128 spatial, BN=NT*32 couts, BK=32. 4 waves in 2x2; per-wave 4xNT tiles.
template<int NT>
__global__ __launch_bounds__(256)
void conv_mfma_k(const u16* __restrict__ in, int Cin,
                 const u16* __restrict__ wb, const float* __restrict__ bias,
                 const u16* __restrict__ skip, int Cout,
                 u16* __restrict__ out, int Cst,
                 int logW, int logH, int relu)
{
    constexpr int BM = 128, BK = 32, BN = NT * 32;
    constexpr int PAD = 40;   // row stride (bf16): 80B -> rotates bank groups, 2-way max
    __shared__ u16 At[BM * PAD];
    __shared__ u16 Bt[BN * PAD];

    const int tid = threadIdx.x;
    const int W = 1 << logW, H = 1 << logH;
    const int mBase = blockIdx.x * BM;
    const int nBase = blockIdx.y * BN;
    const int K = 9 * Cin;

    // A-staging coords: thread -> (m_local, 16-wide k half)
    const int am = tid & 127;
    const int ak = (tid >> 7) * 16;
    const int m = mBase + am;
    const int px = m & (W - 1);
    const int py = (m >> logW) & (H - 1);
    const int pb = m >> (logW + logH);

    const int wid = tid >> 6, lane = tid & 63;
    const int wm = wid >> 1, wn = wid & 1;
    const int fm = lane & 15, fk = (lane >> 4) * 8;

    floatx4 acc[4][NT] = {};

    int tap = 0, cb = 0, dy = -1, dx = -1;
    const int nChunks = K / BK;
    for (int kc = 0; kc < nChunks; ++kc) {
        // ---- stage A (gathered shifted input, uniform tap per chunk)
        {
            int iy = py + dy, ix = px + dx;
            bool ok = ((unsigned)iy < (unsigned)H) & ((unsigned)ix < (unsigned)W);
            uint4v v0 = {0, 0, 0, 0}, v1 = {0, 0, 0, 0};
            if (ok) {
                const u16* sp = in + (size_t)((((pb << logH) + iy) << logW) + ix) * Cin + cb + ak;
                v0 = *(const uint4v*)sp;
                v1 = *(const uint4v*)(sp + 8);
            }
            *(uint4v*)&At[am * PAD + ak]     = v0;
            *(uint4v*)&At[am * PAD + ak + 8] = v1;
        }
        // ---- stage B (weights, fully contiguous rows)
        if constexpr (NT == 4) {
            const u16* sp = wb + (size_t)(nBase + (tid & 127)) * K + kc * BK + (tid >> 7) * 16;
            *(uint4v*)&Bt[(tid & 127) * PAD + (tid >> 7) * 16]     = *(const uint4v*)sp;
            *(uint4v*)&Bt[(tid & 127) * PAD + (tid >> 7) * 16 + 8] = *(const uint4v*)(sp + 8);
        } else {
            const u16* sp = wb + (size_t)(nBase + (tid & 63)) * K + kc * BK + (tid >> 6) * 8;
            *(uint4v*)&Bt[(tid & 63) * PAD + (tid >> 6) * 8] = *(const uint4v*)sp;
        }
        __syncthreads();
        // ---- fragments + MFMA
        bf16x8 af[4], bfr[NT];
#pragma unroll
        for (int mt = 0; mt < 4; ++mt)
            af[mt] = *(const bf16x8*)&At[(wm * 64 + mt * 16 + fm) * PAD + fk];
#pragma unroll
        for (int nt = 0; nt < NT; ++nt)
            bfr[nt] = *(const bf16x8*)&Bt[(wn * (NT * 16) + nt * 16 + fm) * PAD + fk];
#pragma unroll
        for (int mt = 0; mt < 4; ++mt)
#pragma unroll
            for (int nt = 0; nt < NT; ++nt)
                acc[mt][nt] = __builtin_amdgcn_mfma_f32_16x16x32_bf16(af[mt], bfr[nt], acc[mt][nt], 0, 0, 0);
        __syncthreads();
        cb += BK;
        if (cb >= Cin) { cb = 0; ++tap; dy = tap / 3 - 1; dx = tap % 3 - 1; }
    }

    // ---- epilogue: bias (+skip) (+lrelu) -> bf16 NHWC
    const int rq = (lane >> 4) * 4;
#pragma unroll
    for (int nt = 0; nt < NT; ++nt) {
        const int n = nBase + wn * (NT * 16) + nt * 16 + fm;
        const float bn = bias[n];
#pragma unroll
        for (int mt = 0; mt < 4; ++mt) {
            const int mm = mBase + wm * 64 + mt * 16 + rq;
#pragma unroll
            for (int r = 0; r < 4; ++r) {
                float v = acc[mt][nt][r] + bn;
                if (skip) v += b2f(skip[(size_t)(mm + r) * Cout + n]);
                if (relu) v = lrelu_f(v);
                out[(size_t)(mm + r) * Cst + n] = f2b(v);
            }
        }
    }
}

// ---------------- direct NHWC conv3x3 (small Cin), fp32 weights ----------------
template<int CIN, int COUT>
__global__ __launch_bounds__(256)
void conv_direct_k(const u16* __restrict__ in, int Sin,
                   const float* __restrict__ w, const float* __restrict__ bias,
                   u16* __restrict__ out, int Sout,
                   int logW, int logH, int relu, int total)
{
    int m = blockIdx.x * 256 + threadIdx.x;
    if (m >= total) return;
    const int W = 1 << logW, H = 1 << logH;
    const int px = m & (W - 1);
    const int py = (m >> logW) & (H - 1);
    const int pb = m >> (logW + logH);
    float acc[COUT];
#pragma unroll
    for (int o = 0; o < COUT; ++o) acc[o] = bias[o];
    for (int tap = 0; tap < 9; ++tap) {
        int dy = tap / 3 - 1, dx = tap % 3 - 1;
        int iy = py + dy, ix = px + dx;
        if ((unsigned)iy >= (unsigned)H || (unsigned)ix >= (unsigned)W) continue;
        const u16* p = in + (size_t)((((pb << logH) + iy) << logW) + ix) * Sin;
        if constexpr (CIN == 4) {
            u16x4 v = *(const u16x4*)p;
#pragma unroll
            for (int ci = 0; ci < 4; ++ci) {
                float f = b2f(v[ci]);
#pragma unroll
                for (int o = 0; o < COUT; ++o) acc[o] += f * w[(o * CIN + ci) * 9 + tap];
            }
        } else {
#pragma unroll
            for (int c8 = 0; c8 < CIN / 8; ++c8) {
                u16x8 v = *(const u16x8*)(p + c8 * 8);
#pragma unroll
                for (int j = 0; j < 8; ++j) {
                    int ci = c8 * 8 + j;
                    float f = b2f(v[j]);
#pragma unroll
                    for (int o = 0; o < COUT; ++o) acc[o] += f * w[(o * CIN + ci) * 9 + tap];
                }
            }
        }
    }
    size_t ob = (size_t)m * Sout;
#pragma unroll
    for (int o = 0; o < COUT; ++o)
        out[ob + o] = f2b(relu ? lrelu_f(acc[o]) : acc[o]);
}

// ---------------- Haar wt / iwt, NHWC strided ----------------
__global__ __launch_bounds__(256)
void wt_in_k(const float* __restrict__ x, u16* __restrict__ out, int total)
{
    int idx = blockIdx.x * 256 + threadIdx.x;   // (b,h,w) of 8x256x256
    if (idx >= total) return;
    int wq = idx & 255, t = idx >> 8;
    int hq = t & 255, b = t >> 8;
    const float* p = x + ((size_t)b * 512 + 2 * hq) * 512 + 2 * wq;
    float a = p[0], bv = p[1], cv = p[512], d = p[513];
    u16x4 o = { f2b(0.25f * (a + bv + cv + d)),
                f2b(0.25f * (a + bv - cv - d) + 0.5f),
                f2b(0.25f * (a - bv + cv - d) + 0.5f),
                f2b(0.25f * (a - bv - cv + d) + 0.5f) };
    *(u16x4*)&out[(size_t)idx * 4] = o;
}

__global__ __launch_bounds__(256)
void wt_k(const u16* __restrict__ in, int Sin, int logC,
          u16* __restrict__ out, int Sout, int logWo, int logHo, int total)
{
    int idx = blockIdx.x * 256 + threadIdx.x;
    if (idx >= total) return;
    const int C = 1 << logC, Wo = 1 << logWo, Ho = 1 << logHo;
    int c = idx & (C - 1); int t = idx >> logC;
    int wq = t & (Wo - 1); t >>= logWo;
    int hq = t & (Ho - 1); int b = t >> logHo;
    const int Wi = Wo << 1;
    size_t p00 = ((size_t)(b * (Ho << 1) + 2 * hq) * Wi + 2 * wq) * Sin + c;
    float a  = b2f(in[p00]);
    float bv = b2f(in[p00 + Sin]);
    float cv = b2f(in[p00 + (size_t)Wi * Sin]);
    float d  = b2f(in[p00 + (size_t)Wi * Sin + Sin]);
    u16x4 o = { f2b(0.25f * (a + bv + cv + d)),
                f2b(0.25f * (a + bv - cv - d) + 0.5f),
                f2b(0.25f * (a - bv + cv - d) + 0.5f),
                f2b(0.25f * (a - bv - cv + d) + 0.5f) };
    *(u16x4*)&out[((size_t)(b * Ho + hq) * Wo + wq) * Sout + 4 * c] = o;
}

__global__ __launch_bounds__(256)
void iwt_k(const u16* __restrict__ in, int Sin, int logC,
           u16* __restrict__ out, int Sout, int logW, int logH, int total)
{
    int idx = blockIdx.x * 256 + threadIdx.x;
    if (idx >= total) return;
    const int C = 1 << logC, W = 1 << logW, H = 1 << logH;
    int c = idx & (C - 1); int t = idx >> logC;
    int wq = t & (W - 1); t >>= logW;
    int hq = t & (H - 1); int b = t >> logH;
    u16x4 v = *(const u16x4*)&in[((size_t)(b * H + hq) * W + wq) * Sin + 4 * c];
    float y0 = b2f(v[0]);
    float y1 = 2.f * b2f(v[1]) - 1.f;
    float y2 = 2.f * b2f(v[2]) - 1.f;
    float y3 = 2.f * b2f(v[3]) - 1.f;
    float x00 = y0 + 0.5f * ( y1 + y2 + y3);
    float x01 = y0 + 0.5f * ( y1 - y2 - y3);
    float x10 = y0 + 0.5f * (-y1 + y2 - y3);
    float x11 = y0 + 0.5f * (-y1 - y2 + y3);
    const int W2 = W << 1;
    size_t q = ((size_t)(b * (H << 1) + 2 * hq) * W2 + 2 * wq) * Sout + c;
    out[q] = f2b(x00);
    out[q + Sout] = f2b(x01);
    out[q + (size_t)W2 * Sout] = f2b(x10);
    out[q + (size_t)W2 * Sout + Sout] = f2b(x11);
}

__global__ __launch_bounds__(256)
void iwt_out_k(const u16* __restrict__ in, float* __restrict__ out, int total)
{
    int idx = blockIdx.x * 256 + threadIdx.x;   // (b,h,w) of 8x256x256
    if (idx >= total) return;
    int wq = idx & 255, t = idx >> 8;
    int hq = t & 255, b = t >> 8;
    u16x4 v = *(const u16x4*)&in[(size_t)idx * 4];
    float y0 = b2f(v[0]);
    float y1 = 2.f * b2f(v[1]) - 1.f;
    float y2 = 2.f * b2f(v[2]) - 1.f;
    float y3 = 2.f * b2f(v[3]) - 1.f;
    float x00 = y0 + 0.5f * ( y1 + y2 + y3);
    float x01 = y0 + 0.5f * ( y1 - y2 - y3);
    float x10 = y0 + 0.5f * (-y1 + y2 - y3);
    float x11 = y0 + 0.5f * (-y1 - y2 + y3);
    float* q = out + ((size_t)b * 512 + 2 * hq) * 512 + 2 * wq;
    q[0]   = 1.f / (1.f + __expf(-x00));
    q[1]   = 1.f / (1.f + __expf(-x01));
    q[512] = 1.f / (1.f + __expf(-x10));
    q[513] = 1.f / (1.f + __expf(-x11));
}

// ---------------- weight prep: [O][I][3][3] fp32 -> [O][tap][I] bf16 ----------------
__global__ __launch_bounds__(256)
void prep_w_k(const float* __restrict__ src, u16* __restrict__ dst, int logCIN, int total)
{
    int idx = blockIdx.x * 256 + threadIdx.x;
    if (idx >= total) return;
    const int CIN = 1 << logCIN;
    int ci = idx & (CIN - 1);
    int q = idx >> logCIN;
    int tap = q % 9, o = q / 9;
    dst[idx] = f2b(src[((size_t)(o * CIN + ci)) * 9 + tap]);
}

// ---------------------------------------------------------------------------
extern "C" void kernel_launch(void* const* d_in, const int* in_sizes, int n_in,
                              void* d_out, int out_size, void* d_ws, size_t ws_size,
                              hipStream_t stream)
{
    const float* x   = (const float*)d_in[0];
    const float* c1w = (const float*)d_in[1];  const float* c1b = (const float*)d_in[2];
    const float* c2w = (const float*)d_in[3];  const float* c2b = (const float*)d_in[4];
    const float* c3w = (const float*)d_in[5];  const float* c3b = (const float*)d_in[6];
    const float* c4w = (const float*)d_in[7];  const float* c4b = (const float*)d_in[8];
    const float* d1w = (const float*)d_in[9];  const float* d1b = (const float*)d_in[10];
    const float* d2w = (const float*)d_in[11]; const float* d2b = (const float*)d_in[12];
    const float* d3w = (const float*)d_in[13]; const float* d3b = (const float*)d_in[14];
    const float* d4w = (const float*)d_in[15]; const float* d4b = (const float*)d_in[16];

    const size_t MiB = 1u << 20;
    char* base = (char*)d_ws;
    // weight area (0..24 MiB)
    u16* c4wb = (u16*)base;                 // 1024*9216 = 9,437,184
    u16* c3wb = c4wb + 9437184;             // 256*2304  =   589,824
    u16* d4wb = c3wb + 589824;              // 256*4608  = 1,179,648
    u16* d3wb = d4wb + 1179648;             // 64*1152   =    73,728
    u16* c2wb = d3wb + 73728;               // 64*576    =    36,864
    // activation buffers (all NHWC bf16)
    u16* CAT1 = (u16*)(base + 24  * MiB);   // [8,256,256,32]  c1 | u2
    u16* CAT2 = (u16*)(base + 56  * MiB);   // [8,128,128,128] c2 | u3
    u16* CAT3 = (u16*)(base + 88  * MiB);   // [8,64,64,512]   c3 | u4
    u16* D    = (u16*)(base + 120 * MiB);   // W2 -> C4/ic4
    u16* E    = (u16*)(base + 136 * MiB);   // W3 -> W4 -> IC3
    u16* F    = (u16*)(base + 152 * MiB);   // C5 -> IC2 -> IC1
    u16* Hb   = (u16*)(base + 168 * MiB);   // W1 -> IW1  [8,256,256,4]
    float* outp = (float*)d_out;

    auto cdiv = [](int a, int b) { return (a + b - 1) / b; };
    auto prep = [&](const float* s, u16* d, int logCIN, int total) {
        prep_w_k<<<cdiv(total, 256), 256, 0, stream>>>(s, d, logCIN, total);
    };
    auto mfma4 = [&](const u16* in, int Cin, const u16* w, const float* bi, const u16* skip,
                     int Cout, u16* out, int Cst, int logW, int logH) {
        int M = 8 << (logW + logH);
        dim3 g(M / 128, Cout / 128);
        conv_mfma_k<4><<<g, 256, 0, stream>>>(in, Cin, w, bi, skip, Cout, out, Cst, logW, logH, 1);
    };
    auto mfma2 = [&](const u16* in, int Cin, const u16* w, const float* bi,
                     int Cout, u16* out, int Cst, int logW, int logH) {
        int M = 8 << (logW + logH);
        dim3 g(M / 128, Cout / 64);
        conv_mfma_k<2><<<g, 256, 0, stream>>>(in, Cin, w, bi, (const u16*)nullptr, Cout, out, Cst, logW, logH, 1);
    };

    // weight prep (every launch; graph-safe)
    prep(c4w, c4wb, 10, 9437184);
    prep(c3w, c3wb, 8, 589824);
    prep(d4w, d4wb, 9, 1179648);
    prep(d3w, d3wb, 7, 73728);
    prep(c2w, c2wb, 6, 36864);

    const int P256 = 8 * 256 * 256;   // pixels at 256x256
    // w1 = wt(x) -> Hb
    wt_in_k<<<cdiv(P256, 256), 256, 0, stream>>>(x, Hb, P256);
    // c1 = lrelu(conv1(w1)) -> CAT1 ch0..15
    conv_direct_k<4, 16><<<cdiv(P256, 256), 256, 0, stream>>>(Hb, 4, c1w, c1b, CAT1, 32, 8, 8, 1, P256);
    // w2 = wt(c1) -> D
    wt_k<<<cdiv(P256 / 4 * 16, 256), 256, 0, stream>>>(CAT1, 32, 4, D, 64, 7, 7, P256 / 4 * 16);
    // c2 = lrelu(conv2(w2)) -> CAT2 ch0..63
    mfma2(D, 64, c2wb, c2b, 64, CAT2, 128, 7, 7);
    // w3 = wt(c2) -> E
    wt_k<<<cdiv(8 * 64 * 64 * 64, 256), 256, 0, stream>>>(CAT2, 128, 6, E, 256, 6, 6, 8 * 64 * 64 * 64);
    // c3 = lrelu(conv3(w3)) -> CAT3 ch0..255
    mfma4(E, 256, c3wb, c3b, nullptr, 256, CAT3, 512, 6, 6);
    // w4 = wt(c3) -> E
    wt_k<<<cdiv(8 * 32 * 32 * 256, 256), 256, 0, stream>>>(CAT3, 512, 8, E, 1024, 5, 5, 8 * 32 * 32 * 256);
    // c4 = lrelu(conv4(w4)) -> D
    mfma4(E, 1024, c4wb, c4b, nullptr, 1024, D, 1024, 5, 5);
    // c5 = lrelu(conv4(c4)) -> F
    mfma4(D, 1024, c4wb, c4b, nullptr, 1024, F, 1024, 5, 5);
    // ic4 = lrelu(conv4(c5) + w4) -> D
    mfma4(F, 1024, c4wb, c4b, E, 1024, D, 1024, 5, 5);
    // u4 = iwt(ic4) -> CAT3 ch256..511
    iwt_k<<<cdiv(8 * 32 * 32 * 256, 256), 256, 0, stream>>>(D, 1024, 8, CAT3 + 256, 512, 5, 5, 8 * 32 * 32 * 256);
    // ic3 = lrelu(convd4(cat(c3,u4))) -> E
    mfma4(CAT3, 512, d4wb, d4b, nullptr, 256, E, 256, 6, 6);
    // u3 = iwt(ic3) -> CAT2 ch64..127
    iwt_k<<<cdiv(8 * 64 * 64 * 64, 256), 256, 0, stream>>>(E, 256, 6, CAT2 + 64, 128, 6, 6, 8 * 64 * 64 * 64);
    // ic2 = lrelu(convd3(cat(c2,u3))) -> F
    mfma2(CAT2, 128, d3wb, d3b, 64, F, 64, 7, 7);
    // u2 = iwt(ic2) -> CAT1 ch16..31
    iwt_k<<<cdiv(P256 / 4 * 16, 256), 256, 0, stream>>>(F, 64, 4, CAT1 + 16, 32, 7, 7, P256 / 4 * 16);
    // ic1 = lrelu(convd2(cat(c1,u2))) -> F
    conv_direct_k<32, 16><<<cdiv(P256, 256), 256, 0, stream>>>(CAT1, 32, d2w, d2b, F, 16, 8, 8, 1, P256);
    // iw1 = lrelu(convd1(ic1)) -> Hb
    conv_direct_k<16, 4><<<cdiv(P256, 256), 256, 0, stream>>>(F, 16, d1w, d1b, Hb, 4, 8, 8, 1, P256);
    // out = sigmoid(iwt(iw1)) -> d_out
    iwt_out_k<<<cdiv(P256, 256), 256, 0, stream>>>(Hb, outp, P256);
}

// Round 3
// 1297.630 us; speedup vs baseline: 27.1285x; 1.2416x over previous
//
#include <hip/hip_runtime.h>
#include <cstddef>

// ---------------------------------------------------------------------------
// WaveletNet on MI355X — round 3: m97-style K-loop for MFMA convs.
// Zero-padded NHWC inputs (all taps in-bounds) + global_load_lds width-16
// staging into pad-free [row][32] LDS. Haar wt/iwt elementwise, geometry-
// parametrized for padded buffers. Concat via channel-sliced shared buffers.
// ---------------------------------------------------------------------------

typedef unsigned short u16;
typedef unsigned int u32;
typedef __bf16 bf16x8 __attribute__((ext_vector_type(8)));
typedef float floatx4 __attribute__((ext_vector_type(4)));
typedef u16 u16x4 __attribute__((ext_vector_type(4)));
typedef u16 u16x8 __attribute__((ext_vector_type(8)));

__device__ __forceinline__ float b2f(u16 h) {
    union { u32 u; float f; } x; x.u = ((u32)h) << 16; return x.f;
}
__device__ __forceinline__ u16 f2b(float f) {
    union { float f; u32 u; } x; x.f = f;
    return (u16)((x.u + 0x7FFFu + ((x.u >> 16) & 1u)) >> 16);
}
__device__ __forceinline__ float lrelu_f(float v) { return v > 0.f ? v : 0.2f * v; }

// async global->LDS, 16B per lane; LDS dest = wave-uniform base + lane*16
__device__ __forceinline__ void gld16(const u16* g, u16* l) {
    __builtin_amdgcn_global_load_lds(
        (const __attribute__((address_space(1))) u32*)(const void*)g,
        (__attribute__((address_space(3))) u32*)(void*)l, 16, 0, 0);
}

// ---------------- MFMA implicit-GEMM conv3x3, padded NHWC ----------------
// A[m][k], k = tap*Cin+ci; input padded [B][H+2][W+2][Cin], border zero.
// Wb = [Cout][9*Cin]. BM=128, BN=NT*32, BK=32. 4 waves 2x2, 4xNT frag tiles.
template<int NT>
__global__ __launch_bounds__(256)
void conv_mfma_k(const u16* __restrict__ in, int Cin, int iWp, int iImg,
                 const u16* __restrict__ wb, const float* __restrict__ bias,
                 const u16* __restrict__ skip, int sC, int sWp, int sImg, int spad,
                 u16* __restrict__ out, int Cst, int oWp, int oImg, int opad,
                 int logW, int logH)
{
    constexpr int BM = 128, BN = NT * 32;
    __shared__ u16 At[BM * 32];      // 8 KB, row = 32 bf16 = 64 B, no pad
    __shared__ u16 Bt[BN * 32];

    const int tid = threadIdx.x;
    const int wid = tid >> 6, lane = tid & 63;
    const int W = 1 << logW, H = 1 << logH;
    const int mBase = blockIdx.x * BM;
    const int nBase = blockIdx.y * BN;
    const int K = 9 * Cin;
    const int kg = lane & 3;        // 8-elem k-group within 32-chunk
    const int rr = lane >> 2;       // row-within-16 group

    // per-lane loop-invariant global base pointers (tap (-1,-1) == padded (py,px))
    const u16 *gA0, *gA1, *gB0, *gB1 = nullptr;
    {
        int m0 = mBase + wid * 32 + rr;
        int px0 = m0 & (W - 1), py0 = (m0 >> logW) & (H - 1), pb0 = m0 >> (logW + logH);
        gA0 = in + ((size_t)pb0 * iImg + (size_t)py0 * iWp + px0) * Cin + kg * 8;
        int m1 = m0 + 16;
        int px1 = m1 & (W - 1), py1 = (m1 >> logW) & (H - 1), pb1 = m1 >> (logW + logH);
        gA1 = in + ((size_t)pb1 * iImg + (size_t)py1 * iWp + px1) * Cin + kg * 8;
    }
    if constexpr (NT == 4) {
        gB0 = wb + (size_t)(nBase + wid * 32 + rr) * K + kg * 8;
        gB1 = wb + (size_t)(nBase + wid * 32 + 16 + rr) * K + kg * 8;
    } else {
        gB0 = wb + (size_t)(nBase + wid * 16 + rr) * K + kg * 8;
    }
    u16* lA0 = &At[wid * 1024];
    u16* lA1 = &At[wid * 1024 + 512];
    u16* lB0 = (NT == 4) ? &Bt[wid * 1024] : &Bt[wid * 512];
    u16* lB1 = (NT == 4) ? &Bt[wid * 1024 + 512] : nullptr;

    const int wm = wid >> 1, wn = wid & 1;
    const int fm = lane & 15, fkh = (lane >> 4) * 8;

    floatx4 acc[4][NT] = {};

    const int nChunks = K / 32;
    const size_t rowStep = (size_t)(iWp - 2) * Cin;
    int cbn = 0, tap = 0;
    for (int kc = 0; kc < nChunks; ++kc) {
        gld16(gA0, lA0);
        gld16(gA1, lA1);
        gld16(gB0, lB0);
        if constexpr (NT == 4) gld16(gB1, lB1);
        __syncthreads();            // drains vmcnt -> LDS tiles complete

        bf16x8 af[4], bfr[NT];
#pragma unroll
        for (int mt = 0; mt < 4; ++mt)
            af[mt] = *(const bf16x8*)&At[(wm * 64 + mt * 16 + fm) * 32 + fkh];
#pragma unroll
        for (int nt = 0; nt < NT; ++nt)
            bfr[nt] = *(const bf16x8*)&Bt[(wn * (NT * 16) + nt * 16 + fm) * 32 + fkh];
#pragma unroll
        for (int mt = 0; mt < 4; ++mt)
#pragma unroll
            for (int nt = 0; nt < NT; ++nt)
                acc[mt][nt] = __builtin_amdgcn_mfma_f32_16x16x32_bf16(af[mt], bfr[nt], acc[mt][nt], 0, 0, 0);
        __syncthreads();

        // uniform per-chunk pointer advance
        size_t dA = 32;
        cbn += 32;
        if (cbn == Cin) { cbn = 0; ++tap; dA = ((tap % 3 == 0) ? rowStep : (size_t)Cin) - (size_t)(Cin - 32); }
        gA0 += dA; gA1 += dA;
        gB0 += 32;
        if constexpr (NT == 4) gB1 += 32;
    }

    // epilogue: bias (+skip) + lrelu -> bf16 NHWC (padded or flat out)
    const int rq = (lane >> 4) * 4;
#pragma unroll
    for (int mt = 0; mt < 4; ++mt) {
        const int mrow = mBase + wm * 64 + mt * 16 + rq;
#pragma unroll
        for (int r = 0; r < 4; ++r) {
            int m2 = mrow + r;
            int px = m2 & (W - 1), py = (m2 >> logW) & (H - 1), pb = m2 >> (logW + logH);
            size_t ob = ((size_t)pb * oImg + (size_t)(py + opad) * oWp + (px + opad)) * Cst;
            size_t sb = 0;
            if (skip) sb = ((size_t)pb * sImg + (size_t)(py + spad) * sWp + (px + spad)) * sC;
#pragma unroll
            for (int nt = 0; nt < NT; ++nt) {
                int n = nBase + wn * (NT * 16) + nt * 16 + fm;
                float v = acc[mt][nt][r] + bias[n];
                if (skip) v += b2f(skip[sb + n]);
                v = lrelu_f(v);
                out[ob + n] = f2b(v);
            }
        }
    }
}

// ---------------- direct NHWC conv3x3 (small channels), fp32 weights ----------------
template<int CIN, int COUT>
__global__ __launch_bounds__(256)
void conv_direct_k(const u16* __restrict__ in, int Sin,
                   const float* __restrict__ w, const float* __restrict__ bias,
                   u16* __restrict__ out, int Sout,
                   int logW, int logH, int total)
{
    int m = blockIdx.x * 256 + threadIdx.x;
    if (m >= total) return;
    const int W = 1 << logW, H = 1 << logH;
    const int px = m & (W - 1);
    const int py = (m >> logW) & (H - 1);
    const int pb = m >> (logW + logH);
    float acc[COUT];
#pragma unroll
    for (int o = 0; o < COUT; ++o) acc[o] = bias[o];
    for (int tap = 0; tap < 9; ++tap) {
        int dy = tap / 3 - 1, dx = tap % 3 - 1;
        int iy = py + dy, ix = px + dx;
        if ((unsigned)iy >= (unsigned)H || (unsigned)ix >= (unsigned)W) continue;
        const u16* p = in + (size_t)((((pb << logH) + iy) << logW) + ix) * Sin;
        if constexpr (CIN == 4) {
            u16x4 v = *(const u16x4*)p;
#pragma unroll
            for (int ci = 0; ci < 4; ++ci) {
                float f = b2f(v[ci]);
#pragma unroll
                for (int o = 0; o < COUT; ++o) acc[o] += f * w[(o * CIN + ci) * 9 + tap];
            }
        } else {
#pragma unroll
            for (int c8 = 0; c8 < CIN / 8; ++c8) {
                u16x8 v = *(const u16x8*)(p + c8 * 8);
#pragma unroll
                for (int j = 0; j < 8; ++j) {
                    int ci = c8 * 8 + j;
                    float f = b2f(v[j]);
#pragma unroll
                    for (int o = 0; o < COUT; ++o) acc[o] += f * w[(o * CIN + ci) * 9 + tap];
                }
            }
        }
    }
    size_t ob = (size_t)m * Sout;
#pragma unroll
    for (int o = 0; o < COUT; ++o)
        out[ob + o] = f2b(lrelu_f(acc[o]));
}

// ---------------- Haar wt / iwt, geometry-parametrized NHWC ----------------
__global__ __launch_bounds__(256)
void wt_in_k(const float* __restrict__ x, u16* __restrict__ out, int total)
{
    int idx = blockIdx.x * 256 + threadIdx.x;   // (b,h,w) of 8x256x256
    if (idx >= total) return;
    int wq = idx & 255, t = idx >> 8;
    int hq = t & 255, b = t >> 8;
    const float* p = x + ((size_t)b * 512 + 2 * hq) * 512 + 2 * wq;
    float a = p[0], bv = p[1], cv = p[512], d = p[513];
    u16x4 o = { f2b(0.25f * (a + bv + cv + d)),
                f2b(0.25f * (a + bv - cv - d) + 0.5f),
                f2b(0.25f * (a - bv + cv - d) + 0.5f),
                f2b(0.25f * (a - bv - cv + d) + 0.5f) };
    *(u16x4*)&out[(size_t)idx * 4] = o;
}

// in: maybe-padded NHWC [Sin]; out: maybe-padded NHWC [Sout], channels 4c+band
__global__ __launch_bounds__(256)
void wt_k(const u16* __restrict__ in, int Sin, int iWp, int iImg, int ipad,
          u16* __restrict__ out, int Sout, int oWp, int oImg, int opad,
          int logC, int logWo, int logHo, int total)
{
    int idx = blockIdx.x * 256 + threadIdx.x;
    if (idx >= total) return;
    const int C = 1 << logC, Wo = 1 << logWo, Ho = 1 << logHo;
    int c = idx & (C - 1); int t = idx >> logC;
    int wq = t & (Wo - 1); t >>= logWo;
    int hq = t & (Ho - 1); int b = t >> logHo;
    size_t p00 = ((size_t)b * iImg + (size_t)(2 * hq + ipad) * iWp + (2 * wq + ipad)) * Sin + c;
    float a  = b2f(in[p00]);
    float bv = b2f(in[p00 + Sin]);
    float cv = b2f(in[p00 + (size_t)iWp * Sin]);
    float d  = b2f(in[p00 + (size_t)iWp * Sin + Sin]);
    u16x4 o = { f2b(0.25f * (a + bv + cv + d)),
                f2b(0.25f * (a + bv - cv - d) + 0.5f),
                f2b(0.25f * (a - bv + cv - d) + 0.5f),
                f2b(0.25f * (a - bv - cv + d) + 0.5f) };
    *(u16x4*)&out[((size_t)b * oImg + (size_t)(hq + opad) * oWp + (wq + opad)) * Sout + 4 * c] = o;
}

// in: flat NHWC (unpadded), channels 4c+band; out: maybe-padded NHWC
__global__ __launch_bounds__(256)
void iwt_k(const u16* __restrict__ in, int Sin, int logC, int logW, int logH,
           u16* __restrict__ out, int Sout, int oWp, int oImg, int opad, int total)
{
    int idx = blockIdx.x * 256 + threadIdx.x;
    if (idx >= total) return;
    const int C = 1 << logC, W = 1 << logW;
    int c = idx & (C - 1); int t = idx >> logC;
    int wq = t & (W - 1); t >>= logW;
    int hq = t & ((1 << logH) - 1); int b = t >> logH;
    u16x4 v = *(const u16x4*)&in[(size_t)((((b << logH) + hq) << logW) + wq) * Sin + 4 * c];
    float y0 = b2f(v[0]);
    float y1 = 2.f * b2f(v[1]) - 1.f;
    float y2 = 2.f * b2f(v[2]) - 1.f;
    float y3 = 2.f * b2f(v[3]) - 1.f;
    float x00 = y0 + 0.5f * ( y1 + y2 + y3);
    float x01 = y0 + 0.5f * ( y1 - y2 - y3);
    float x10 = y0 + 0.5f * (-y1 + y2 - y3);
    float x11 = y0 + 0.5f * (-y1 - y2 + y3);
    size_t q = ((size_t)b * oImg + (size_t)(2 * hq + opad) * oWp + (2 * wq + opad)) * Sout + c;
    out[q] = f2b(x00);
    out[q + Sout] = f2b(x01);
    out[q + (size_t)oWp * Sout] = f2b(x10);
    out[q + (size_t)oWp * Sout + Sout] = f2b(x11);
}

__global__ __launch_bounds__(256)
void iwt_out_k(const u16* __restrict__ in, float* __restrict__ out, int total)
{
    int idx = blockIdx.x * 256 + threadIdx.x;   // (b,h,w) of 8x256x256
    if (idx >= total) return;
    int wq = idx & 255, t = idx >> 8;
    int hq = t & 255, b = t >> 8;
    u16x4 v = *(const u16x4*)&in[(size_t)idx * 4];
    float y0 = b2f(v[0]);
    float y1 = 2.f * b2f(v[1]) - 1.f;
    float y2 = 2.f * b2f(v[2]) - 1.f;
    float y3 = 2.f * b2f(v[3]) - 1.f;
    float x00 = y0 + 0.5f * ( y1 + y2 + y3);
    float x01 = y0 + 0.5f * ( y1 - y2 - y3);
    float x10 = y0 + 0.5f * (-y1 + y2 - y3);
    float x11 = y0 + 0.5f * (-y1 - y2 + y3);
    float* q = out + ((size_t)b * 512 + 2 * hq) * 512 + 2 * wq;
    q[0]   = 1.f / (1.f + __expf(-x00));
    q[1]   = 1.f / (1.f + __expf(-x01));
    q[512] = 1.f / (1.f + __expf(-x10));
    q[513] = 1.f / (1.f + __expf(-x11));
}

// ---------------- weight prep: [O][I][3][3] fp32 -> [O][tap][I] bf16 ----------------
__global__ __launch_bounds__(256)
void prep_w_k(const float* __restrict__ src, u16* __restrict__ dst, int logCIN, int total)
{
    int idx = blockIdx.x * 256 + threadIdx.x;
    if (idx >= total) return;
    const int CIN = 1 << logCIN;
    int ci = idx & (CIN - 1);
    int q = idx >> logCIN;
    int tap = q % 9, o = q / 9;
    dst[idx] = f2b(src[((size_t)(o * CIN + ci)) * 9 + tap]);
}

// ---------------- zero the 1-pixel border of a padded NHWC buffer ----------------
__global__ __launch_bounds__(256)
void zb_k(u16* __restrict__ buf, int Wp, int Hp, int C, int total)
{
    int idx = blockIdx.x * 256 + threadIdx.x;
    if (idx >= total) return;
    int c8 = idx % (C / 8); int t = idx / (C / 8);
    int nbp = 2 * Wp + 2 * (Hp - 2);
    int p = t % nbp; int b = t / nbp;
    int y, x;
    if (p < Wp) { y = 0; x = p; }
    else if (p < 2 * Wp) { y = Hp - 1; x = p - Wp; }
    else { int q = p - 2 * Wp; y = 1 + (q >> 1); x = (q & 1) ? Wp - 1 : 0; }
    u16x8 z = {0, 0, 0, 0, 0, 0, 0, 0};
    *(u16x8*)&buf[((size_t)b * Hp * Wp + (size_t)y * Wp + x) * C + c8 * 8] = z;
}

// ---------------------------------------------------------------------------
extern "C" void kernel_launch(void* const* d_in, const int* in_sizes, int n_in,
                              void* d_out, int out_size, void* d_ws, size_t ws_size,
                              hipStream_t stream)
{
    const float* x   = (const float*)d_in[0];
    const float* c1w = (const float*)d_in[1];  const float* c1b = (const float*)d_in[2];
    const float* c2w = (const float*)d_in[3];  const float* c2b = (const float*)d_in[4];
    const float* c3w = (const float*)d_in[5];  const float* c3b = (const float*)d_in[6];
    const float* c4w = (const float*)d_in[7];  const float* c4b = (const float*)d_in[8];
    const float* d1w = (const float*)d_in[9];  const float* d1b = (const float*)d_in[10];
    const float* d2w = (const float*)d_in[11]; const float* d2b = (const float*)d_in[12];
    const float* d3w = (const float*)d_in[13]; const float* d3b = (const float*)d_in[14];
    const float* d4w = (const float*)d_in[15]; const float* d4b = (const float*)d_in[16];

    const size_t MiB = 1u << 20;
    char* base = (char*)d_ws;
    // weights [0, 23 MiB)
    u16* c4wb = (u16*)base;                  // 9,437,184
    u16* c3wb = c4wb + 9437184;              //   589,824
    u16* d4wb = c3wb + 589824;               // 1,179,648
    u16* d3wb = d4wb + 1179648;              //    73,728
    u16* c2wb = d3wb + 73728;                //    36,864
    // activations
    u16* CAT1  = (u16*)(base + 23  * MiB);   // [8,256,256,32] flat: c1 | u2
    u16* CAT2p = (u16*)(base + 55  * MiB);   // [8,130,130,128] padded: c2 | u3
    u16* CAT3p = (u16*)(base + 89  * MiB);   // [8,66,66,512]  padded: c3 | u4
    u16* P1    = (u16*)(base + 124 * MiB);   // W2p -> W4p -> IC2
    u16* P2    = (u16*)(base + 143 * MiB);   // W3p -> C4p -> IC4 -> IC1
    u16* P3    = (u16*)(base + 162 * MiB);   // W1 -> C5p -> IC3 -> IW1
    float* outp = (float*)d_out;

    u16* W2p = P1; u16* W4p = P1; u16* IC2 = P1;
    u16* W3p = P2; u16* C4p = P2; u16* IC4 = P2; u16* IC1 = P2;
    u16* W1  = P3; u16* C5p = P3; u16* IC3 = P3; u16* IW1 = P3;

    auto cdiv = [](int a, int b) { return (a + b - 1) / b; };
    auto prep = [&](const float* s, u16* d, int logCIN, int total) {
        prep_w_k<<<cdiv(total, 256), 256, 0, stream>>>(s, d, logCIN, total);
    };
    auto zb = [&](u16* buf, int Wp, int Hp, int C) {
        int total = 8 * (2 * Wp + 2 * (Hp - 2)) * (C / 8);
        zb_k<<<cdiv(total, 256), 256, 0, stream>>>(buf, Wp, Hp, C, total);
    };
    auto mfma4 = [&](const u16* in, int Cin, int iWp, int iImg,
                     const u16* w, const float* bi,
                     const u16* skip, int sC, int sWp, int sImg, int spad,
                     int Cout, u16* out, int Cst, int oWp, int oImg, int opad,
                     int logW, int logH) {
        int M = 8 << (logW + logH);
        dim3 g(M / 128, Cout / 128);
        conv_mfma_k<4><<<g, 256, 0, stream>>>(in, Cin, iWp, iImg, w, bi,
                                              skip, sC, sWp, sImg, spad,
                                              out, Cst, oWp, oImg, opad, logW, logH);
    };
    auto mfma2 = [&](const u16* in, int Cin, int iWp, int iImg,
                     const u16* w, const float* bi,
                     int Cout, u16* out, int Cst, int oWp, int oImg, int opad,
                     int logW, int logH) {
        int M = 8 << (logW + logH);
        dim3 g(M / 128, Cout / 64);
        conv_mfma_k<2><<<g, 256, 0, stream>>>(in, Cin, iWp, iImg, w, bi,
                                              (const u16*)nullptr, 0, 0, 0, 0,
                                              out, Cst, oWp, oImg, opad, logW, logH);
    };

    // weight prep
    prep(c4w, c4wb, 10, 9437184);
    prep(c3w, c3wb, 8, 589824);
    prep(d4w, d4wb, 9, 1179648);
    prep(d3w, d3wb, 7, 73728);
    prep(c2w, c2wb, 6, 36864);
    // borders whose slots have no earlier tenant
    zb(W2p, 130, 130, 64);
    zb(W3p, 66, 66, 256);
    zb(CAT2p, 130, 130, 128);
    zb(CAT3p, 66, 66, 512);

    const int P256 = 8 * 256 * 256;
    const int T2M = 2097152;   // 8*128*128*16 == 8*64*64*64 == 8*32*32*256

    // w1 = wt(x) -> W1 (flat [8,256,256,4])
    wt_in_k<<<cdiv(P256, 256), 256, 0, stream>>>(x, W1, P256);
    // c1 -> CAT1 ch0..15 (direct, fp32 weights)
    conv_direct_k<4, 16><<<cdiv(P256, 256), 256, 0, stream>>>(W1, 4, c1w, c1b, CAT1, 32, 8, 8, P256);
    zb(C5p, 34, 34, 1024);                      // P3 free of W1 now
    // w2 = wt(c1) -> W2p padded [8,130,130,64]
    wt_k<<<cdiv(T2M, 256), 256, 0, stream>>>(CAT1, 32, 256, 65536, 0,
                                             W2p, 64, 130, 16900, 1, 4, 7, 7, T2M);
    // c2 -> CAT2p interior ch0..63
    mfma2(W2p, 64, 130, 16900, c2wb, c2b, 64, CAT2p, 128, 130, 16900, 1, 7, 7);
    zb(W4p, 34, 34, 1024);                      // P1 free of W2p now
    // w3 = wt(c2) -> W3p padded [8,66,66,256]
    wt_k<<<cdiv(T2M, 256), 256, 0, stream>>>(CAT2p, 128, 130, 16900, 1,
                                             W3p, 256, 66, 4356, 1, 6, 6, 6, T2M);
    // c3 -> CAT3p interior ch0..255
    mfma4(W3p, 256, 66, 4356, c3wb, c3b, nullptr, 0, 0, 0, 0,
          256, CAT3p, 512, 66, 4356, 1, 6, 6);
    zb(C4p, 34, 34, 1024);                      // P2 free of W3p now
    // w4 = wt(c3) -> W4p padded [8,34,34,1024]
    wt_k<<<cdiv(T2M, 256), 256, 0, stream>>>(CAT3p, 512, 66, 4356, 1,
                                             W4p, 1024, 34, 1156, 1, 8, 5, 5, T2M);
    // c4 -> C4p padded
    mfma4(W4p, 1024, 34, 1156, c4wb, c4b, nullptr, 0, 0, 0, 0,
          1024, C4p, 1024, 34, 1156, 1, 5, 5);
    // c5 -> C5p padded
    mfma4(C4p, 1024, 34, 1156, c4wb, c4b, nullptr, 0, 0, 0, 0,
          1024, C5p, 1024, 34, 1156, 1, 5, 5);
    // ic4 = lrelu(conv4(c5) + w4) -> IC4 flat [8,32,32,1024]
    mfma4(C5p, 1024, 34, 1156, c4wb, c4b, W4p, 1024, 34, 1156, 1,
          1024, IC4, 1024, 32, 1024, 0, 5, 5);
    // u4 = iwt(ic4) -> CAT3p interior ch256..511
    iwt_k<<<cdiv(T2M, 256), 256, 0, stream>>>(IC4, 1024, 8, 5, 5,
                                              CAT3p + 256, 512, 66, 4356, 1, T2M);
    // ic3 = lrelu(convd4(cat3)) -> IC3 flat [8,64,64,256]
    mfma4(CAT3p, 512, 66, 4356, d4wb, d4b, nullptr, 0, 0, 0, 0,
          256, IC3, 256, 64, 4096, 0, 6, 6);
    // u3 = iwt(ic3) -> CAT2p interior ch64..127
    iwt_k<<<cdiv(T2M, 256), 256, 0, stream>>>(IC3, 256, 6, 6, 6,
                                              CAT2p + 64, 128, 130, 16900, 1, T2M);
    // ic2 = lrelu(convd3(cat2)) -> IC2 flat [8,128,128,64]
    mfma2(CAT2p, 128, 130, 16900, d3wb, d3b, 64, IC2, 64, 128, 16384, 0, 7, 7);
    // u2 = iwt(ic2) -> CAT1 ch16..31 (flat)
    iwt_k<<<cdiv(T2M, 256), 256, 0, stream>>>(IC2, 64, 4, 7, 7,
                                              CAT1 + 16, 32, 256, 65536, 0, T2M);
    // ic1 = lrelu(convd2(cat1)) -> IC1 flat [8,256,256,16]
    conv_direct_k<32, 16><<<cdiv(P256, 256), 256, 0, stream>>>(CAT1, 32, d2w, d2b, IC1, 16, 8, 8, P256);
    // iw1 = lrelu(convd1(ic1)) -> IW1 flat [8,256,256,4]
    conv_direct_k<16, 4><<<cdiv(P256, 256), 256, 0, stream>>>(IC1, 16, d1w, d1b, IW1, 4, 8, 8, P256);
    // out = sigmoid(iwt(iw1))
    iwt_out_k<<<cdiv(P256, 256), 256, 0, stream>>>(IW1, outp, P256);
}

// Round 4
// 1168.367 us; speedup vs baseline: 30.1298x; 1.1106x over previous
//
#include <hip/hip_runtime.h>
#include <cstddef>

// ---------------------------------------------------------------------------
// WaveletNet on MI355X — round 4: occupancy fix. NT=2 (128x64) tiles for all
// MFMA convs -> 1024 blocks = 4 blocks/CU (was 2). convd2 MFMA-ized (N=16).
// Zero-padded NHWC + global_load_lds width-16, m97 K-loop structure.
// ---------------------------------------------------------------------------

typedef unsigned short u16;
typedef unsigned int u32;
typedef __bf16 bf16x8 __attribute__((ext_vector_type(8)));
typedef float floatx4 __attribute__((ext_vector_type(4)));
typedef u16 u16x4 __attribute__((ext_vector_type(4)));
typedef u16 u16x8 __attribute__((ext_vector_type(8)));

__device__ __forceinline__ float b2f(u16 h) {
    union { u32 u; float f; } x; x.u = ((u32)h) << 16; return x.f;
}
__device__ __forceinline__ u16 f2b(float f) {
    union { float f; u32 u; } x; x.f = f;
    return (u16)((x.u + 0x7FFFu + ((x.u >> 16) & 1u)) >> 16);
}
__device__ __forceinline__ float lrelu_f(float v) { return v > 0.f ? v : 0.2f * v; }

// async global->LDS, 16B per lane; LDS dest = wave-uniform base + lane*16
__device__ __forceinline__ void gld16(const u16* g, u16* l) {
    __builtin_amdgcn_global_load_lds(
        (const __attribute__((address_space(1))) u32*)(const void*)g,
        (__attribute__((address_space(3))) u32*)(void*)l, 16, 0, 0);
}

// ---------------- MFMA implicit-GEMM conv3x3, padded NHWC ----------------
// A[m][k], k = tap*Cin+ci; input padded [B][H+2][W+2][Cin], border zero.
// Wb = [Cout][9*Cin]. BM=128, BN=NT*32, BK=32. 4 waves 2x2, 4xNT frag tiles.
template<int NT>
__global__ __launch_bounds__(256)
void conv_mfma_k(const u16* __restrict__ in, int Cin, int iWp, int iImg,
                 const u16* __restrict__ wb, const float* __restrict__ bias,
                 const u16* __restrict__ skip, int sC, int sWp, int sImg, int spad,
                 u16* __restrict__ out, int Cst, int oWp, int oImg, int opad,
                 int logW, int logH)
{
    constexpr int BM = 128, BN = NT * 32;
    __shared__ u16 At[BM * 32];      // 8 KB, row = 32 bf16 = 64 B, no pad
    __shared__ u16 Bt[BN * 32];

    const int tid = threadIdx.x;
    const int wid = tid >> 6, lane = tid & 63;
    const int W = 1 << logW, H = 1 << logH;
    const int mBase = blockIdx.x * BM;
    const int nBase = blockIdx.y * BN;
    const int K = 9 * Cin;
    const int kg = lane & 3;        // 8-elem k-group within 32-chunk
    const int rr = lane >> 2;       // row-within-16 group

    // per-lane loop-invariant global base pointers (tap (-1,-1) == padded (py,px))
    const u16 *gA0, *gA1, *gB0, *gB1 = nullptr;
    {
        int m0 = mBase + wid * 32 + rr;
        int px0 = m0 & (W - 1), py0 = (m0 >> logW) & (H - 1), pb0 = m0 >> (logW + logH);
        gA0 = in + ((size_t)pb0 * iImg + (size_t)py0 * iWp + px0) * Cin + kg * 8;
        int m1 = m0 + 16;
        int px1 = m1 & (W - 1), py1 = (m1 >> logW) & (H - 1), pb1 = m1 >> (logW + logH);
        gA1 = in + ((size_t)pb1 * iImg + (size_t)py1 * iWp + px1) * Cin + kg * 8;
    }
    if constexpr (NT == 4) {
        gB0 = wb + (size_t)(nBase + wid * 32 + rr) * K + kg * 8;
        gB1 = wb + (size_t)(nBase + wid * 32 + 16 + rr) * K + kg * 8;
    } else {
        gB0 = wb + (size_t)(nBase + wid * 16 + rr) * K + kg * 8;
    }
    u16* lA0 = &At[wid * 1024];
    u16* lA1 = &At[wid * 1024 + 512];
    u16* lB0 = (NT == 4) ? &Bt[wid * 1024] : &Bt[wid * 512];
    u16* lB1 = (NT == 4) ? &Bt[wid * 1024 + 512] : nullptr;

    const int wm = wid >> 1, wn = wid & 1;
    const int fm = lane & 15, fkh = (lane >> 4) * 8;

    floatx4 acc[4][NT] = {};

    const int nChunks = K / 32;
    const size_t rowStep = (size_t)(iWp - 2) * Cin;
    int cbn = 0, tap = 0;
    for (int kc = 0; kc < nChunks; ++kc) {
        gld16(gA0, lA0);
        gld16(gA1, lA1);
        gld16(gB0, lB0);
        if constexpr (NT == 4) gld16(gB1, lB1);
        __syncthreads();            // drains vmcnt -> LDS tiles complete

        bf16x8 af[4], bfr[NT];
#pragma unroll
        for (int mt = 0; mt < 4; ++mt)
            af[mt] = *(const bf16x8*)&At[(wm * 64 + mt * 16 + fm) * 32 + fkh];
#pragma unroll
        for (int nt = 0; nt < NT; ++nt)
            bfr[nt] = *(const bf16x8*)&Bt[(wn * (NT * 16) + nt * 16 + fm) * 32 + fkh];
#pragma unroll
        for (int mt = 0; mt < 4; ++mt)
#pragma unroll
            for (int nt = 0; nt < NT; ++nt)
                acc[mt][nt] = __builtin_amdgcn_mfma_f32_16x16x32_bf16(af[mt], bfr[nt], acc[mt][nt], 0, 0, 0);
        __syncthreads();

        // uniform per-chunk pointer advance
        size_t dA = 32;
        cbn += 32;
        if (cbn == Cin) { cbn = 0; ++tap; dA = ((tap % 3 == 0) ? rowStep : (size_t)Cin) - (size_t)(Cin - 32); }
        gA0 += dA; gA1 += dA;
        gB0 += 32;
        if constexpr (NT == 4) gB1 += 32;
    }

    // epilogue: bias (+skip) + lrelu -> bf16 NHWC (padded or flat out)
    const int rq = (lane >> 4) * 4;
#pragma unroll
    for (int mt = 0; mt < 4; ++mt) {
        const int mrow = mBase + wm * 64 + mt * 16 + rq;
#pragma unroll
        for (int r = 0; r < 4; ++r) {
            int m2 = mrow + r;
            int px = m2 & (W - 1), py = (m2 >> logW) & (H - 1), pb = m2 >> (logW + logH);
            size_t ob = ((size_t)pb * oImg + (size_t)(py + opad) * oWp + (px + opad)) * Cst;
            size_t sb = 0;
            if (skip) sb = ((size_t)pb * sImg + (size_t)(py + spad) * sWp + (px + spad)) * sC;
#pragma unroll
            for (int nt = 0; nt < NT; ++nt) {
                int n = nBase + wn * (NT * 16) + nt * 16 + fm;
                float v = acc[mt][nt][r] + bias[n];
                if (skip) v += b2f(skip[sb + n]);
                v = lrelu_f(v);
                out[ob + n] = f2b(v);
            }
        }
    }
}

// ---------------- MFMA conv3x3, Cin=32 -> Cout=16 (convd2), padded in, flat out ----
__global__ __launch_bounds__(256)
void conv_n16_k(const u16* __restrict__ in, int iWp, int iImg,
                const u16* __restrict__ wb, const float* __restrict__ bias,
                u16* __restrict__ out, int logW, int logH)
{
    __shared__ u16 At[128 * 32];    // 8 KB
    __shared__ u16 Bt[16 * 32];     // 1 KB
    const int tid = threadIdx.x;
    const int wid = tid >> 6, lane = tid & 63;
    const int W = 1 << logW, H = 1 << logH;
    const int mBase = blockIdx.x * 128;
    const int kg = lane & 3, rr = lane >> 2;

    const u16 *gA0, *gA1;
    {
        int m0 = mBase + wid * 32 + rr;
        int px0 = m0 & (W - 1), py0 = (m0 >> logW) & (H - 1), pb0 = m0 >> (logW + logH);
        gA0 = in + ((size_t)pb0 * iImg + (size_t)py0 * iWp + px0) * 32 + kg * 8;
        int m1 = m0 + 16;
        int px1 = m1 & (W - 1), py1 = (m1 >> logW) & (H - 1), pb1 = m1 >> (logW + logH);
        gA1 = in + ((size_t)pb1 * iImg + (size_t)py1 * iWp + px1) * 32 + kg * 8;
    }
    const u16* gB = wb + (size_t)rr * 288 + kg * 8;   // 16 rows (rr<16 used)
    u16* lA0 = &At[wid * 1024];
    u16* lA1 = &At[wid * 1024 + 512];

    const int fm = lane & 15, fkh = (lane >> 4) * 8;
    floatx4 acc[2] = {};
    const size_t rowStep = (size_t)(iWp - 2) * 32;

    for (int tap = 0; tap < 9; ++tap) {
        gld16(gA0, lA0);
        gld16(gA1, lA1);
        if (wid == 0) gld16(gB, &Bt[0]);
        __syncthreads();
        bf16x8 bf = *(const bf16x8*)&Bt[fm * 32 + fkh];
#pragma unroll
        for (int mt = 0; mt < 2; ++mt) {
            bf16x8 af = *(const bf16x8*)&At[(wid * 32 + mt * 16 + fm) * 32 + fkh];
            acc[mt] = __builtin_amdgcn_mfma_f32_16x16x32_bf16(af, bf, acc[mt], 0, 0, 0);
        }
        __syncthreads();
        size_t dA = (tap % 3 == 2) ? rowStep : (size_t)32;
        gA0 += dA; gA1 += dA; gB += 32;
    }

    const int rq = (lane >> 4) * 4;
    const float bn = bias[fm];
#pragma unroll
    for (int mt = 0; mt < 2; ++mt) {
#pragma unroll
        for (int r = 0; r < 4; ++r) {
            int m2 = mBase + wid * 32 + mt * 16 + rq + r;
            out[(size_t)m2 * 16 + fm] = f2b(lrelu_f(acc[mt][r] + bn));
        }
    }
}

// ---------------- direct NHWC conv3x3 (small channels), fp32 weights ----------------
template<int CIN, int COUT>
__global__ __launch_bounds__(256)
void conv_direct_k(const u16* __restrict__ in, int Sin,
                   const float* __restrict__ w, const float* __restrict__ bias,
                   u16* __restrict__ out, int Sout, int oWp, int oImg, int opad,
                   int logW, int logH, int total)
{
    int m = blockIdx.x * 256 + threadIdx.x;
    if (m >= total) return;
    const int W = 1 << logW, H = 1 << logH;
    const int px = m & (W - 1);
    const int py = (m >> logW) & (H - 1);
    const int pb = m >> (logW + logH);
    float acc[COUT];
#pragma unroll
    for (int o = 0; o < COUT; ++o) acc[o] = bias[o];
    for (int tap = 0; tap < 9; ++tap) {
        int dy = tap / 3 - 1, dx = tap % 3 - 1;
        int iy = py + dy, ix = px + dx;
        if ((unsigned)iy >= (unsigned)H || (unsigned)ix >= (unsigned)W) continue;
        const u16* p = in + (size_t)((((pb << logH) + iy) << logW) + ix) * Sin;
        if constexpr (CIN == 4) {
            u16x4 v = *(const u16x4*)p;
#pragma unroll
            for (int ci = 0; ci < 4; ++ci) {
                float f = b2f(v[ci]);
#pragma unroll
                for (int o = 0; o < COUT; ++o) acc[o] += f * w[(o * CIN + ci) * 9 + tap];
            }
        } else {
#pragma unroll
            for (int c8 = 0; c8 < CIN / 8; ++c8) {
                u16x8 v = *(const u16x8*)(p + c8 * 8);
#pragma unroll
                for (int j = 0; j < 8; ++j) {
                    int ci = c8 * 8 + j;
                    float f = b2f(v[j]);
#pragma unroll
                    for (int o = 0; o < COUT; ++o) acc[o] += f * w[(o * CIN + ci) * 9 + tap];
                }
            }
        }
    }
    size_t ob = ((size_t)pb * oImg + (size_t)(py + opad) * oWp + (px + opad)) * Sout;
#pragma unroll
    for (int o = 0; o < COUT; ++o)
        out[ob + o] = f2b(lrelu_f(acc[o]));
}

// ---------------- Haar wt / iwt, geometry-parametrized NHWC ----------------
__global__ __launch_bounds__(256)
void wt_in_k(const float* __restrict__ x, u16* __restrict__ out, int total)
{
    int idx = blockIdx.x * 256 + threadIdx.x;   // (b,h,w) of 8x256x256
    if (idx >= total) return;
    int wq = idx & 255, t = idx >> 8;
    int hq = t & 255, b = t >> 8;
    const float* p = x + ((size_t)b * 512 + 2 * hq) * 512 + 2 * wq;
    float a = p[0], bv = p[1], cv = p[512], d = p[513];
    u16x4 o = { f2b(0.25f * (a + bv + cv + d)),
                f2b(0.25f * (a + bv - cv - d) + 0.5f),
                f2b(0.25f * (a - bv + cv - d) + 0.5f),
                f2b(0.25f * (a - bv - cv + d) + 0.5f) };
    *(u16x4*)&out[(size_t)idx * 4] = o;
}

// in: maybe-padded NHWC [Sin]; out: maybe-padded NHWC [Sout], channels 4c+band
__global__ __launch_bounds__(256)
void wt_k(const u16* __restrict__ in, int Sin, int iWp, int iImg, int ipad,
          u16* __restrict__ out, int Sout, int oWp, int oImg, int opad,
          int logC, int logWo, int logHo, int total)
{
    int idx = blockIdx.x * 256 + threadIdx.x;
    if (idx >= total) return;
    const int C = 1 << logC, Wo = 1 << logWo, Ho = 1 << logHo;
    int c = idx & (C - 1); int t = idx >> logC;
    int wq = t & (Wo - 1); t >>= logWo;
    int hq = t & (Ho - 1); int b = t >> logHo;
    size_t p00 = ((size_t)b * iImg + (size_t)(2 * hq + ipad) * iWp + (2 * wq + ipad)) * Sin + c;
    float a  = b2f(in[p00]);
    float bv = b2f(in[p00 + Sin]);
    float cv = b2f(in[p00 + (size_t)iWp * Sin]);
    float d  = b2f(in[p00 + (size_t)iWp * Sin + Sin]);
    u16x4 o = { f2b(0.25f * (a + bv + cv + d)),
                f2b(0.25f * (a + bv - cv - d) + 0.5f),
                f2b(0.25f * (a - bv + cv - d) + 0.5f),
                f2b(0.25f * (a - bv - cv + d) + 0.5f) };
    *(u16x4*)&out[((size_t)b * oImg + (size_t)(hq + opad) * oWp + (wq + opad)) * Sout + 4 * c] = o;
}

// in: flat NHWC (unpadded), channels 4c+band; out: maybe-padded NHWC
__global__ __launch_bounds__(256)
void iwt_k(const u16* __restrict__ in, int Sin, int logC, int logW, int logH,
           u16* __restrict__ out, int Sout, int oWp, int oImg, int opad, int total)
{
    int idx = blockIdx.x * 256 + threadIdx.x;
    if (idx >= total) return;
    const int C = 1 << logC, W = 1 << logW;
    int c = idx & (C - 1); int t = idx >> logC;
    int wq = t & (W - 1); t >>= logW;
    int hq = t & ((1 << logH) - 1); int b = t >> logH;
    u16x4 v = *(const u16x4*)&in[(size_t)((((b << logH) + hq) << logW) + wq) * Sin + 4 * c];
    float y0 = b2f(v[0]);
    float y1 = 2.f * b2f(v[1]) - 1.f;
    float y2 = 2.f * b2f(v[2]) - 1.f;
    float y3 = 2.f * b2f(v[3]) - 1.f;
    float x00 = y0 + 0.5f * ( y1 + y2 + y3);
    float x01 = y0 + 0.5f * ( y1 - y2 - y3);
    float x10 = y0 + 0.5f * (-y1 + y2 - y3);
    float x11 = y0 + 0.5f * (-y1 - y2 + y3);
    size_t q = ((size_t)b * oImg + (size_t)(2 * hq + opad) * oWp + (2 * wq + opad)) * Sout + c;
    out[q] = f2b(x00);
    out[q + Sout] = f2b(x01);
    out[q + (size_t)oWp * Sout] = f2b(x10);
    out[q + (size_t)oWp * Sout + Sout] = f2b(x11);
}

__global__ __launch_bounds__(256)
void iwt_out_k(const u16* __restrict__ in, float* __restrict__ out, int total)
{
    int idx = blockIdx.x * 256 + threadIdx.x;   // (b,h,w) of 8x256x256
    if (idx >= total) return;
    int wq = idx & 255, t = idx >> 8;
    int hq = t & 255, b = t >> 8;
    u16x4 v = *(const u16x4*)&in[(size_t)idx * 4];
    float y0 = b2f(v[0]);
    float y1 = 2.f * b2f(v[1]) - 1.f;
    float y2 = 2.f * b2f(v[2]) - 1.f;
    float y3 = 2.f * b2f(v[3]) - 1.f;
    float x00 = y0 + 0.5f * ( y1 + y2 + y3);
    float x01 = y0 + 0.5f * ( y1 - y2 - y3);
    float x10 = y0 + 0.5f * (-y1 + y2 - y3);
    float x11 = y0 + 0.5f * (-y1 - y2 + y3);
    float* q = out + ((size_t)b * 512 + 2 * hq) * 512 + 2 * wq;
    q[0]   = 1.f / (1.f + __expf(-x00));
    q[1]   = 1.f / (1.f + __expf(-x01));
    q[512] = 1.f / (1.f + __expf(-x10));
    q[513] = 1.f / (1.f + __expf(-x11));
}

// ---------------- weight prep: [O][I][3][3] fp32 -> [O][tap][I] bf16 ----------------
__global__ __launch_bounds__(256)
void prep_w_k(const float* __restrict__ src, u16* __restrict__ dst, int logCIN, int total)
{
    int idx = blockIdx.x * 256 + threadIdx.x;
    if (idx >= total) return;
    const int CIN = 1 << logCIN;
    int ci = idx & (CIN - 1);
    int q = idx >> logCIN;
    int tap = q % 9, o = q / 9;
    dst[idx] = f2b(src[((size_t)(o * CIN + ci)) * 9 + tap]);
}

// ---------------- zero the 1-pixel border of a padded NHWC buffer ----------------
__global__ __launch_bounds__(256)
void zb_k(u16* __restrict__ buf, int Wp, int Hp, int C, int total)
{
    int idx = blockIdx.x * 256 + threadIdx.x;
    if (idx >= total) return;
    int c8 = idx % (C / 8); int t = idx / (C / 8);
    int nbp = 2 * Wp + 2 * (Hp - 2);
    int p = t % nbp; int b = t / nbp;
    int y, x;
    if (p < Wp) { y = 0; x = p; }
    else if (p < 2 * Wp) { y = Hp - 1; x = p - Wp; }
    else { int q = p - 2 * Wp; y = 1 + (q >> 1); x = (q & 1) ? Wp - 1 : 0; }
    u16x8 z = {0, 0, 0, 0, 0, 0, 0, 0};
    *(u16x8*)&buf[((size_t)b * Hp * Wp + (size_t)y * Wp + x) * C + c8 * 8] = z;
}

// ---------------------------------------------------------------------------
extern "C" void kernel_launch(void* const* d_in, const int* in_sizes, int n_in,
                              void* d_out, int out_size, void* d_ws, size_t ws_size,
                              hipStream_t stream)
{
    const float* x   = (const float*)d_in[0];
    const float* c1w = (const float*)d_in[1];  const float* c1b = (const float*)d_in[2];
    const float* c2w = (const float*)d_in[3];  const float* c2b = (const float*)d_in[4];
    const float* c3w = (const float*)d_in[5];  const float* c3b = (const float*)d_in[6];
    const float* c4w = (const float*)d_in[7];  const float* c4b = (const float*)d_in[8];
    const float* d1w = (const float*)d_in[9];  const float* d1b = (const float*)d_in[10];
    const float* d2w = (const float*)d_in[11]; const float* d2b = (const float*)d_in[12];
    const float* d3w = (const float*)d_in[13]; const float* d3b = (const float*)d_in[14];
    const float* d4w = (const float*)d_in[15]; const float* d4b = (const float*)d_in[16];

    const size_t MiB = 1u << 20;
    char* base = (char*)d_ws;
    // weights [0, 22 MiB)
    u16* c4wb = (u16*)base;                  // 9,437,184
    u16* c3wb = c4wb + 9437184;              //   589,824
    u16* d4wb = c3wb + 589824;               // 1,179,648
    u16* d3wb = d4wb + 1179648;              //    73,728
    u16* c2wb = d3wb + 73728;                //    36,864
    u16* d2wb = c2wb + 36864;                //     4,608
    // activations
    u16* CAT1p = (u16*)(base + 22  * MiB);   // [8,258,258,32]  padded: c1 | u2
    u16* CAT2p = (u16*)(base + 55  * MiB);   // [8,130,130,128] padded: c2 | u3
    u16* CAT3p = (u16*)(base + 88  * MiB);   // [8,66,66,512]   padded: c3 | u4
    u16* P1    = (u16*)(base + 123 * MiB);   // W2p -> W4p -> IC2
    u16* P2    = (u16*)(base + 142 * MiB);   // W3p -> C4p -> IC4 -> IC1
    u16* P3    = (u16*)(base + 161 * MiB);   // W1 -> C5p -> IC3 -> IW1
    float* outp = (float*)d_out;

    u16* W2p = P1; u16* W4p = P1; u16* IC2 = P1;
    u16* W3p = P2; u16* C4p = P2; u16* IC4 = P2; u16* IC1 = P2;
    u16* W1  = P3; u16* C5p = P3; u16* IC3 = P3; u16* IW1 = P3;

    auto cdiv = [](int a, int b) { return (a + b - 1) / b; };
    auto prep = [&](const float* s, u16* d, int logCIN, int total) {
        prep_w_k<<<cdiv(total, 256), 256, 0, stream>>>(s, d, logCIN, total);
    };
    auto zb = [&](u16* buf, int Wp, int Hp, int C) {
        int total = 8 * (2 * Wp + 2 * (Hp - 2)) * (C / 8);
        zb_k<<<cdiv(total, 256), 256, 0, stream>>>(buf, Wp, Hp, C, total);
    };
    auto mfma2 = [&](const u16* in, int Cin, int iWp, int iImg,
                     const u16* w, const float* bi,
                     const u16* skip, int sC, int sWp, int sImg, int spad,
                     int Cout, u16* out, int Cst, int oWp, int oImg, int opad,
                     int logW, int logH) {
        int M = 8 << (logW + logH);
        dim3 g(M / 128, Cout / 64);
        conv_mfma_k<2><<<g, 256, 0, stream>>>(in, Cin, iWp, iImg, w, bi,
                                              skip, sC, sWp, sImg, spad,
                                              out, Cst, oWp, oImg, opad, logW, logH);
    };

    // weight prep
    prep(c4w, c4wb, 10, 9437184);
    prep(c3w, c3wb, 8, 589824);
    prep(d4w, d4wb, 9, 1179648);
    prep(d3w, d3wb, 7, 73728);
    prep(c2w, c2wb, 6, 36864);
    prep(d2w, d2wb, 5, 4608);
    // borders whose slots have no earlier tenant
    zb(CAT1p, 258, 258, 32);
    zb(W2p, 130, 130, 64);
    zb(W3p, 66, 66, 256);
    zb(CAT2p, 130, 130, 128);
    zb(CAT3p, 66, 66, 512);

    const int P256 = 8 * 256 * 256;
    const int T2M = 2097152;   // 8*128*128*16 == 8*64*64*64 == 8*32*32*256
    const int I258 = 258 * 258;   // padded 256-image plane

    // w1 = wt(x) -> W1 (flat [8,256,256,4])
    wt_in_k<<<cdiv(P256, 256), 256, 0, stream>>>(x, W1, P256);
    // c1 -> CAT1p interior ch0..15 (direct, fp32 weights)
    conv_direct_k<4, 16><<<cdiv(P256, 256), 256, 0, stream>>>(
        W1, 4, c1w, c1b, CAT1p, 32, 258, I258, 1, 8, 8, P256);
    zb(C5p, 34, 34, 1024);                      // P3 free of W1 now
    // w2 = wt(c1) -> W2p padded [8,130,130,64]
    wt_k<<<cdiv(T2M, 256), 256, 0, stream>>>(CAT1p, 32, 258, I258, 1,
                                             W2p, 64, 130, 16900, 1, 4, 7, 7, T2M);
    // c2 -> CAT2p interior ch0..63
    mfma2(W2p, 64, 130, 16900, c2wb, c2b, nullptr, 0, 0, 0, 0,
          64, CAT2p, 128, 130, 16900, 1, 7, 7);
    zb(W4p, 34, 34, 1024);                      // P1 free of W2p now
    // w3 = wt(c2) -> W3p padded [8,66,66,256]
    wt_k<<<cdiv(T2M, 256), 256, 0, stream>>>(CAT2p, 128, 130, 16900, 1,
                                             W3p, 256, 66, 4356, 1, 6, 6, 6, T2M);
    // c3 -> CAT3p interior ch0..255
    mfma2(W3p, 256, 66, 4356, c3wb, c3b, nullptr, 0, 0, 0, 0,
          256, CAT3p, 512, 66, 4356, 1, 6, 6);
    zb(C4p, 34, 34, 1024);                      // P2 free of W3p now
    // w4 = wt(c3) -> W4p padded [8,34,34,1024]
    wt_k<<<cdiv(T2M, 256), 256, 0, stream>>>(CAT3p, 512, 66, 4356, 1,
                                             W4p, 1024, 34, 1156, 1, 8, 5, 5, T2M);
    // c4 -> C4p padded
    mfma2(W4p, 1024, 34, 1156, c4wb, c4b, nullptr, 0, 0, 0, 0,
          1024, C4p, 1024, 34, 1156, 1, 5, 5);
    // c5 -> C5p padded
    mfma2(C4p, 1024, 34, 1156, c4wb, c4b, nullptr, 0, 0, 0, 0,
          1024, C5p, 1024, 34, 1156, 1, 5, 5);
    // ic4 = lrelu(conv4(c5) + w4) -> IC4 flat [8,32,32,1024]
    mfma2(C5p, 1024, 34, 1156, c4wb, c4b, W4p, 1024, 34, 1156, 1,
          1024, IC4, 1024, 32, 1024, 0, 5, 5);
    // u4 = iwt(ic4) -> CAT3p interior ch256..511
    iwt_k<<<cdiv(T2M, 256), 256, 0, stream>>>(IC4, 1024, 8, 5, 5,
                                              CAT3p + 256, 512, 66, 4356, 1, T2M);
    // ic3 = lrelu(convd4(cat3)) -> IC3 flat [8,64,64,256]
    mfma2(CAT3p, 512, 66, 4356, d4wb, d4b, nullptr, 0, 0, 0, 0,
          256, IC3, 256, 64, 4096, 0, 6, 6);
    // u3 = iwt(ic3) -> CAT2p interior ch64..127
    iwt_k<<<cdiv(T2M, 256), 256, 0, stream>>>(IC3, 256, 6, 6, 6,
                                              CAT2p + 64, 128, 130, 16900, 1, T2M);
    // ic2 = lrelu(convd3(cat2)) -> IC2 flat [8,128,128,64]
    mfma2(CAT2p, 128, 130, 16900, d3wb, d3b, nullptr, 0, 0, 0, 0,
          64, IC2, 64, 128, 16384, 0, 7, 7);
    // u2 = iwt(ic2) -> CAT1p interior ch16..31
    iwt_k<<<cdiv(T2M, 256), 256, 0, stream>>>(IC2, 64, 4, 7, 7,
                                              CAT1p + 16, 32, 258, I258, 1, T2M);
    // ic1 = lrelu(convd2(cat1)) -> IC1 flat [8,256,256,16]  (MFMA, N=16)
    conv_n16_k<<<dim3(P256 / 128), 256, 0, stream>>>(CAT1p, 258, I258, d2wb, d2b, IC1, 8, 8);
    // iw1 = lrelu(convd1(ic1)) -> IW1 flat [8,256,256,4]
    conv_direct_k<16, 4><<<cdiv(P256, 256), 256, 0, stream>>>(
        IC1, 16, d1w, d1b, IW1, 4, 256, 65536, 0, 8, 8, P256);
    // out = sigmoid(iwt(iw1))
    iwt_out_k<<<cdiv(P256, 256), 256, 0, stream>>>(IW1, outp, P256);
}